// Round 9
// baseline (269.629 us; speedup 1.0000x reference)
//
#include <hip/hip_runtime.h>

#define H 0.1f

typedef float float4v __attribute__((ext_vector_type(4)));

__device__ __forceinline__ float bcast_lane(float v, int l) {
    return __int_as_float(__builtin_amdgcn_readlane(__float_as_int(v), l));
}

// ---- prep1: table (Wk,Wv) ∥ bounds (ptr) ∥ rootflag (mask) -----------------
__global__ void __launch_bounds__(256) prep1_kernel(
    const float* __restrict__ key_emb, const float* __restrict__ val_emb,
    const float* __restrict__ lw, const float* __restrict__ lb,
    float* __restrict__ Wk, float* __restrict__ Wv, int K,
    const int* __restrict__ erow, int* __restrict__ ptr, int n, int E,
    const int* __restrict__ roots, int* __restrict__ mask, int R,
    int TBLK, int BBLK)
{
    const int bid = blockIdx.x;
    if (bid < TBLK) {
        const int wv = bid * 4 + ((int)threadIdx.x >> 6);
        const int lane = threadIdx.x & 63;
        if (wv < 2 * K) {
            const int which = wv >= K;
            const int k = which ? wv - K : wv;
            float4v wreg[16];
            const float* wp = lw + (size_t)lane * 64;
#pragma unroll
            for (int q = 0; q < 16; ++q) wreg[q] = *(const float4v*)(wp + 4 * q);
            const float* emb = which ? val_emb : key_emb;
            float ev = emb[k * 64 + lane];
            float acc = which ? 0.f : lb[lane];
#pragma unroll
            for (int q = 0; q < 16; ++q)
#pragma unroll
                for (int j = 0; j < 4; ++j)
                    acc = fmaf(bcast_lane(ev, 4 * q + j), wreg[q][j], acc);
            (which ? Wv : Wk)[k * 64 + lane] = acc;
        }
    } else if (bid < TBLK + BBLK) {
        int e = (bid - TBLK) * 256 + threadIdx.x;
        if (e < E) {
            int b = erow[e];
            int a = (e == 0) ? -1 : erow[e - 1];
            for (int v = a + 1; v <= b; ++v) ptr[v] = e;
            if (e == E - 1)
                for (int v = b + 1; v <= n; ++v) ptr[v] = E;
        }
    } else {
        int i = (bid - TBLK - BBLK) * 256 + threadIdx.x;
        if (i < R) mask[roots[i]] = 1;
    }
}

// ---- prep2: init2 (X0) ∥ mark neighbors-of-roots (mask2) -------------------
__global__ void __launch_bounds__(256) prep2_kernel(
    const int* __restrict__ xnode, const float* __restrict__ Wk,
    const float* __restrict__ Wv, float* __restrict__ X0, int n,
    const int* __restrict__ erow, const int* __restrict__ ecol,
    const int* __restrict__ mask, int* __restrict__ mask2, int E, int IBLK)
{
    const int bid = blockIdx.x;
    if (bid < IBLK) {
        const int lane = threadIdx.x & 63;
        const int v = (bid * 256 + (int)threadIdx.x) >> 6;
        if (v < n) {
            unsigned k0 = (unsigned)__builtin_amdgcn_readfirstlane(xnode[2 * v + 0]);
            unsigned k1 = (unsigned)__builtin_amdgcn_readfirstlane(xnode[2 * v + 1]);
            float p = Wk[(k0 << 6) + lane] + Wv[(k1 << 6) + lane];
            X0[((unsigned)v << 6) + lane] = p > 0.f ? p : 0.f;
        }
    } else {
        int e = (bid - IBLK) * 256 + threadIdx.x;
        if (e < E && mask[erow[e]]) mask2[ecol[e]] = 1;
    }
}

// ---- wave step, TWO nodes per wave with interleaved gather chains ----------
// Doubles outstanding 256B row-loads per wave (latency-bound regime).
// lane = dim. A = node 2w, B = node 2w+1; csr ranges are adjacent:
// A=[b0,m), B=[m,e1) with m=ptr[2w+1].
template <bool MASKED>
__global__ void __launch_bounds__(256) wave_step2(
    const float* __restrict__ Xin, const float* __restrict__ Xm1,
    float* __restrict__ Xout, const int* __restrict__ ptr,
    const int* __restrict__ csr, int n,
    const int* __restrict__ mask, const int* __restrict__ mask2)
{
    const int lane = threadIdx.x & 63;
    const int w = (int)((blockIdx.x * blockDim.x + threadIdx.x) >> 6);
    const int v0 = w * 2;
    if (v0 >= n) return;
    const int v1 = v0 + 1;
    bool aA = true, aB = (v1 < n);
    if (MASKED) {
        aA = (__builtin_amdgcn_readfirstlane(mask[v0]) |
              __builtin_amdgcn_readfirstlane(mask2[v0])) != 0;
        if (aB)
            aB = (__builtin_amdgcn_readfirstlane(mask[v1]) |
                  __builtin_amdgcn_readfirstlane(mask2[v1])) != 0;
        if (!aA && !aB) return;
    }
    int b0 = __builtin_amdgcn_readfirstlane(ptr[v0]);
    int m  = __builtin_amdgcn_readfirstlane(ptr[v1]);
    int e1 = aB ? __builtin_amdgcn_readfirstlane(ptr[v0 + 2]) : m;

    const float* Xl = Xin + lane;
    float sA0 = 0.f, sA1 = 0.f, sA2 = 0.f, sA3 = 0.f;
    float sB0 = 0.f, sB1 = 0.f, sB2 = 0.f, sB3 = 0.f;
    int kA = aA ? b0 : m;
    int kB = m;

    // interleaved main loop: 8 loads in flight (4 per node)
    while (kA + 4 <= m && kB + 4 <= e1) {
        unsigned a0 = (unsigned)csr[kA + 0], a1 = (unsigned)csr[kA + 1];
        unsigned a2 = (unsigned)csr[kA + 2], a3 = (unsigned)csr[kA + 3];
        unsigned c0 = (unsigned)csr[kB + 0], c1 = (unsigned)csr[kB + 1];
        unsigned c2 = (unsigned)csr[kB + 2], c3 = (unsigned)csr[kB + 3];
        sA0 += Xl[a0 << 6];
        sA1 += Xl[a1 << 6];
        sA2 += Xl[a2 << 6];
        sA3 += Xl[a3 << 6];
        sB0 += Xl[c0 << 6];
        sB1 += Xl[c1 << 6];
        sB2 += Xl[c2 << 6];
        sB3 += Xl[c3 << 6];
        kA += 4;
        kB += 4;
    }
    // drain A
    for (; kA + 4 <= m; kA += 4) {
        unsigned a0 = (unsigned)csr[kA + 0], a1 = (unsigned)csr[kA + 1];
        unsigned a2 = (unsigned)csr[kA + 2], a3 = (unsigned)csr[kA + 3];
        sA0 += Xl[a0 << 6];
        sA1 += Xl[a1 << 6];
        sA2 += Xl[a2 << 6];
        sA3 += Xl[a3 << 6];
    }
    for (; kA < m; ++kA) sA0 += Xl[(unsigned)csr[kA] << 6];
    // drain B
    for (; kB + 4 <= e1; kB += 4) {
        unsigned c0 = (unsigned)csr[kB + 0], c1 = (unsigned)csr[kB + 1];
        unsigned c2 = (unsigned)csr[kB + 2], c3 = (unsigned)csr[kB + 3];
        sB0 += Xl[c0 << 6];
        sB1 += Xl[c1 << 6];
        sB2 += Xl[c2 << 6];
        sB3 += Xl[c3 << 6];
    }
    for (; kB < e1; ++kB) sB0 += Xl[(unsigned)csr[kB] << 6];

    if (aA) {
        const unsigned base0 = ((unsigned)v0 << 6) + lane;
        float x = Xin[base0];
        float xm1 = __builtin_nontemporal_load(&Xm1[base0]);
        float s = (sA0 + sA1) + (sA2 + sA3);
        float lap = fmaf((float)(m - b0), x, -s);
        Xout[base0] = fmaf(-(H * H), lap, (x + x) - xm1);
    }
    if (aB) {
        const unsigned base1 = ((unsigned)v1 << 6) + lane;
        float x = Xin[base1];
        float xm1 = __builtin_nontemporal_load(&Xm1[base1]);
        float s = (sB0 + sB1) + (sB2 + sB3);
        float lap = fmaf((float)(e1 - m), x, -s);
        Xout[base1] = fmaf(-(H * H), lap, (x + x) - xm1);
    }
}

// ---- scalar gather body (used once per root in root_osc_final) -------------
__device__ __forceinline__ float wave_update(
    const float* __restrict__ Xin, float x, float xm1, int lane, int b, int e,
    const int* __restrict__ csr)
{
    const float* Xl = Xin + lane;
    float s0 = 0.f, s1 = 0.f, s2 = 0.f, s3 = 0.f;
    float s4 = 0.f, s5 = 0.f, s6 = 0.f, s7 = 0.f;
    int k = b;
    for (; k + 8 <= e; k += 8) {
        unsigned n0 = (unsigned)csr[k + 0], n1 = (unsigned)csr[k + 1];
        unsigned n2 = (unsigned)csr[k + 2], n3 = (unsigned)csr[k + 3];
        unsigned n4 = (unsigned)csr[k + 4], n5 = (unsigned)csr[k + 5];
        unsigned n6 = (unsigned)csr[k + 6], n7 = (unsigned)csr[k + 7];
        s0 += Xl[n0 << 6];
        s1 += Xl[n1 << 6];
        s2 += Xl[n2 << 6];
        s3 += Xl[n3 << 6];
        s4 += Xl[n4 << 6];
        s5 += Xl[n5 << 6];
        s6 += Xl[n6 << 6];
        s7 += Xl[n7 << 6];
    }
    if (k + 4 <= e) {
        unsigned n0 = (unsigned)csr[k + 0], n1 = (unsigned)csr[k + 1];
        unsigned n2 = (unsigned)csr[k + 2], n3 = (unsigned)csr[k + 3];
        s0 += Xl[n0 << 6];
        s1 += Xl[n1 << 6];
        s2 += Xl[n2 << 6];
        s3 += Xl[n3 << 6];
        k += 4;
    }
    for (; k < e; ++k) s0 += Xl[(unsigned)csr[k] << 6];
    float s = ((s0 + s1) + (s2 + s3)) + ((s4 + s5) + (s6 + s7));
    float lap = fmaf((float)(e - b), x, -s);
    return fmaf(-(H * H), lap, (x + x) - xm1);
}

// ---- root_osc + inlined step-8 + final projection --------------------------
__global__ void __launch_bounds__(64) root_osc_final(
    const float* __restrict__ Xall, const int* __restrict__ roots,
    const float* __restrict__ osc_a, const float* __restrict__ Bw,
    const float* __restrict__ Bb, const float* __restrict__ fw,
    const int* __restrict__ ptr, const int* __restrict__ csr,
    float* __restrict__ out, int n, int R, int nout, size_t nd)
{
    const int lane = threadIdx.x;
    const int r = blockIdx.x;
    if (r >= R) return;
    const int v = __builtin_amdgcn_readfirstlane(roots[r]);

    const float* P7 = Xall + 7 * nd;
    const float* P6 = Xall + 6 * nd;
    const unsigned base = ((unsigned)v << 6) + lane;
    int b = __builtin_amdgcn_readfirstlane(ptr[v]);
    int e = __builtin_amdgcn_readfirstlane(ptr[v + 1]);
    float x8 = wave_update(P7, P7[base], P6[base], lane, b, e, csr);

    float hin[9], hout[9];

    {   // pass 0: layer 0, zprev = X^s (same step)
        float4v wreg[16];
        const float* wp = Bw + (size_t)lane * 64;
#pragma unroll
        for (int q = 0; q < 16; ++q) wreg[q] = *(const float4v*)(wp + 4 * q);
        const float aj = osc_a[lane];
        const float bj = Bb[lane];
        float z = 0.f, u = 0.f;
#pragma unroll
        for (int s = 1; s <= 8; ++s) {
            float zp = (s < 8) ? Xall[(size_t)s * nd + base] : x8;
            float acc = fmaf(aj, z, bj);
#pragma unroll
            for (int q = 0; q < 16; ++q)
#pragma unroll
                for (int j = 0; j < 4; ++j)
                    acc = fmaf(bcast_lane(zp, 4 * q + j), wreg[q][j], acc);
            float t = acc > 0.f ? acc : 0.f;
            u += H * t;
            z += H * u;
            hout[s] = z;
        }
    }

    auto pass = [&](int j, int prev_step) {
        float4v wreg[16];
        const float* wp = Bw + (size_t)j * 4096 + (size_t)lane * 64;
#pragma unroll
        for (int q = 0; q < 16; ++q) wreg[q] = *(const float4v*)(wp + 4 * q);
        const float aj = osc_a[j * 64 + lane];
        const float bj = Bb[j * 64 + lane];
        float z = 0.f, u = 0.f;
#pragma unroll
        for (int s = 1; s <= 8; ++s) {
            float zp = prev_step ? hin[s - 1] : hin[s];
            float acc = fmaf(aj, z, bj);
#pragma unroll
            for (int q = 0; q < 16; ++q)
#pragma unroll
                for (int jj = 0; jj < 4; ++jj)
                    acc = fmaf(bcast_lane(zp, 4 * q + jj), wreg[q][jj], acc);
            float t = acc > 0.f ? acc : 0.f;
            u += H * t;
            z += H * u;
            hout[s] = z;
        }
    };

    hin[0] = 0.f;
#pragma unroll
    for (int i = 1; i <= 8; ++i) hin[i] = hout[i];
    pass(1, 0);                     // layer1: zprev = z0^s (same step)
    hin[0] = 0.f;
#pragma unroll
    for (int i = 1; i <= 8; ++i) hin[i] = hout[i];
    pass(2, 1);                     // layer2: zprev = z1^{s-1}
    hin[0] = 0.f;
#pragma unroll
    for (int i = 1; i <= 8; ++i) hin[i] = hout[i];
    pass(3, 1);                     // layer3: zprev = z2^{s-1}

    float z3 = hout[8];
    for (int o = 0; o < nout; ++o) {
        float p = z3 * fw[o * 64 + lane];
#pragma unroll
        for (int off = 32; off > 0; off >>= 1)
            p += __shfl_xor(p, off);
        if (lane == 0) out[r * nout + o] = p;
    }
}

extern "C" void kernel_launch(void* const* d_in, const int* in_sizes, int n_in,
                              void* d_out, int out_size, void* d_ws, size_t ws_size,
                              hipStream_t stream)
{
    const int*   xnode   = (const int*)d_in[0];
    const int*   edge    = (const int*)d_in[1];
    const int*   roots   = (const int*)d_in[2];
    const float* key_emb = (const float*)d_in[3];
    const float* val_emb = (const float*)d_in[4];
    const float* lw      = (const float*)d_in[5];
    const float* lb      = (const float*)d_in[6];
    const float* osc_a   = (const float*)d_in[7];
    const float* Bw      = (const float*)d_in[8];
    const float* Bb      = (const float*)d_in[9];
    const float* fw      = (const float*)d_in[10];

    const int n = in_sizes[0] / 2;
    const int E = in_sizes[1] / 2;
    const int R = in_sizes[2];
    const int K = in_sizes[3] / 64;
    const int nout = out_size / R;
    const int* erow = edge;           // sorted ascending (np.unique axis=1)
    const int* ecol = edge + E;       // adjacency array of the row-CSR, in place

    const size_t nd = (size_t)n * 64;
    float* Xall  = (float*)d_ws;                     // 8*nd (planes 0..7)
    float* Wk    = Xall + 8 * nd;                    // K*64
    float* Wv    = Wk + (size_t)K * 64;              // K*64
    int*   ptr   = (int*)(Wv + (size_t)K * 64);      // n+1
    int*   mask  = ptr + n + 1;                      // n
    int*   mask2 = mask + n;                         // n

    hipMemsetAsync(mask, 0, (size_t)(2 * n) * sizeof(int), stream);

    const int TBLK = (2 * K + 3) / 4;
    const int BBLK = (E + 255) / 256;
    const int RBLK = (R + 255) / 256;
    prep1_kernel<<<TBLK + BBLK + RBLK, 256, 0, stream>>>(
        key_emb, val_emb, lw, lb, Wk, Wv, K, erow, ptr, n, E,
        roots, mask, R, TBLK, BBLK);

    const int IBLK = (n * 64 + 255) / 256;
    const int MBLK = (E + 255) / 256;
    prep2_kernel<<<IBLK + MBLK, 256, 0, stream>>>(
        xnode, Wk, Wv, Xall, n, erow, ecol, mask, mask2, E, IBLK);

    const int nwaves  = (n + 1) / 2;  // 2 nodes per wave
    const int nblocks = (nwaves + 3) / 4;
    for (int s = 1; s <= 6; ++s) {    // step s: reads planes s-1, s-2; writes s
        const float* xin = Xall + (size_t)(s - 1) * nd;
        const float* xm1 = (s == 1) ? xin : Xall + (size_t)(s - 2) * nd;
        wave_step2<false><<<nblocks, 256, 0, stream>>>(
            xin, xm1, Xall + (size_t)s * nd, ptr, ecol, n, nullptr, nullptr);
    }
    // step 7: reads planes 6,5; writes plane 7; cone-restricted
    wave_step2<true><<<nblocks, 256, 0, stream>>>(
        Xall + 6 * nd, Xall + 5 * nd, Xall + 7 * nd, ptr, ecol, n, mask, mask2);

    root_osc_final<<<R, 64, 0, stream>>>(
        Xall, roots, osc_a, Bw, Bb, fw, ptr, ecol,
        (float*)d_out, n, R, nout, nd);
}

// Round 10
// 237.471 us; speedup vs baseline: 1.1354x; 1.1354x over previous
//
#include <hip/hip_runtime.h>

#define H 0.1f

typedef float float4v __attribute__((ext_vector_type(4)));

__device__ __forceinline__ float bcast_lane(float v, int l) {
    return __int_as_float(__builtin_amdgcn_readlane(__float_as_int(v), l));
}

// ---- prep1: table (Wk,Wv) ∥ bounds (ptr) ∥ rootflag (mask) -----------------
__global__ void __launch_bounds__(256) prep1_kernel(
    const float* __restrict__ key_emb, const float* __restrict__ val_emb,
    const float* __restrict__ lw, const float* __restrict__ lb,
    float* __restrict__ Wk, float* __restrict__ Wv, int K,
    const int* __restrict__ erow, int* __restrict__ ptr, int n, int E,
    const int* __restrict__ roots, int* __restrict__ mask, int R,
    int TBLK, int BBLK)
{
    const int bid = blockIdx.x;
    if (bid < TBLK) {
        const int wv = bid * 4 + ((int)threadIdx.x >> 6);
        const int lane = threadIdx.x & 63;
        if (wv < 2 * K) {
            const int which = wv >= K;
            const int k = which ? wv - K : wv;
            float4v wreg[16];
            const float* wp = lw + (size_t)lane * 64;
#pragma unroll
            for (int q = 0; q < 16; ++q) wreg[q] = *(const float4v*)(wp + 4 * q);
            const float* emb = which ? val_emb : key_emb;
            float ev = emb[k * 64 + lane];
            float acc = which ? 0.f : lb[lane];
#pragma unroll
            for (int q = 0; q < 16; ++q)
#pragma unroll
                for (int j = 0; j < 4; ++j)
                    acc = fmaf(bcast_lane(ev, 4 * q + j), wreg[q][j], acc);
            (which ? Wv : Wk)[k * 64 + lane] = acc;
        }
    } else if (bid < TBLK + BBLK) {
        int e = (bid - TBLK) * 256 + threadIdx.x;
        if (e < E) {
            int b = erow[e];
            int a = (e == 0) ? -1 : erow[e - 1];
            for (int v = a + 1; v <= b; ++v) ptr[v] = e;
            if (e == E - 1)
                for (int v = b + 1; v <= n; ++v) ptr[v] = E;
        }
    } else {
        int i = (bid - TBLK - BBLK) * 256 + threadIdx.x;
        if (i < R) mask[roots[i]] = 1;
    }
}

// ---- prep2: init2 (X0) ∥ mark neighbors-of-roots (mask2) -------------------
__global__ void __launch_bounds__(256) prep2_kernel(
    const int* __restrict__ xnode, const float* __restrict__ Wk,
    const float* __restrict__ Wv, float* __restrict__ X0, int n,
    const int* __restrict__ erow, const int* __restrict__ ecol,
    const int* __restrict__ mask, int* __restrict__ mask2, int E, int IBLK)
{
    const int bid = blockIdx.x;
    if (bid < IBLK) {
        const int lane = threadIdx.x & 63;
        const int v = (bid * 256 + (int)threadIdx.x) >> 6;
        if (v < n) {
            unsigned k0 = (unsigned)__builtin_amdgcn_readfirstlane(xnode[2 * v + 0]);
            unsigned k1 = (unsigned)__builtin_amdgcn_readfirstlane(xnode[2 * v + 1]);
            float p = Wk[(k0 << 6) + lane] + Wv[(k1 << 6) + lane];
            X0[((unsigned)v << 6) + lane] = p > 0.f ? p : 0.f;
        }
    } else {
        int e = (bid - IBLK) * 256 + threadIdx.x;
        if (e < E && mask[erow[e]]) mask2[ecol[e]] = 1;
    }
}

// ---- scalar gather body (R6's best-measured form) --------------------------
__device__ __forceinline__ float wave_update(
    const float* __restrict__ Xin, float x, float xm1, int lane, int b, int e,
    const int* __restrict__ csr)
{
    const float* Xl = Xin + lane;
    float s0 = 0.f, s1 = 0.f, s2 = 0.f, s3 = 0.f;
    float s4 = 0.f, s5 = 0.f, s6 = 0.f, s7 = 0.f;
    int k = b;
    for (; k + 8 <= e; k += 8) {
        unsigned n0 = (unsigned)csr[k + 0], n1 = (unsigned)csr[k + 1];
        unsigned n2 = (unsigned)csr[k + 2], n3 = (unsigned)csr[k + 3];
        unsigned n4 = (unsigned)csr[k + 4], n5 = (unsigned)csr[k + 5];
        unsigned n6 = (unsigned)csr[k + 6], n7 = (unsigned)csr[k + 7];
        s0 += Xl[n0 << 6];
        s1 += Xl[n1 << 6];
        s2 += Xl[n2 << 6];
        s3 += Xl[n3 << 6];
        s4 += Xl[n4 << 6];
        s5 += Xl[n5 << 6];
        s6 += Xl[n6 << 6];
        s7 += Xl[n7 << 6];
    }
    if (k + 4 <= e) {
        unsigned n0 = (unsigned)csr[k + 0], n1 = (unsigned)csr[k + 1];
        unsigned n2 = (unsigned)csr[k + 2], n3 = (unsigned)csr[k + 3];
        s0 += Xl[n0 << 6];
        s1 += Xl[n1 << 6];
        s2 += Xl[n2 << 6];
        s3 += Xl[n3 << 6];
        k += 4;
    }
    for (; k < e; ++k) s0 += Xl[(unsigned)csr[k] << 6];
    float s = ((s0 + s1) + (s2 + s3)) + ((s4 + s5) + (s6 + s7));
    float lap = fmaf((float)(e - b), x, -s);
    return fmaf(-(H * H), lap, (x + x) - xm1);
}

// ---- wave layer: 1 node per wave, 3-term leapfrog --------------------------
template <bool MASKED>
__global__ void __launch_bounds__(256) wave_step(
    const float* __restrict__ Xin, const float* __restrict__ Xm1,
    float* __restrict__ Xout, const int* __restrict__ ptr,
    const int* __restrict__ csr, int n,
    const int* __restrict__ mask, const int* __restrict__ mask2)
{
    const int lane = threadIdx.x & 63;
    const int v = (int)((blockIdx.x * blockDim.x + threadIdx.x) >> 6);
    if (v >= n) return;
    if (MASKED) {
        if (!(__builtin_amdgcn_readfirstlane(mask[v]) |
              __builtin_amdgcn_readfirstlane(mask2[v]))) return;
    }
    const unsigned base = ((unsigned)v << 6) + lane;
    int b = __builtin_amdgcn_readfirstlane(ptr[v]);
    int e = __builtin_amdgcn_readfirstlane(ptr[v + 1]);
    float x = Xin[base];
    float xm1 = __builtin_nontemporal_load(&Xm1[base]);   // last use of plane s-2
    Xout[base] = wave_update(Xin, x, xm1, lane, b, e, csr);
}

// ---- root_osc + inlined step-8 + final projection --------------------------
__global__ void __launch_bounds__(64) root_osc_final(
    const float* __restrict__ Xall, const int* __restrict__ roots,
    const float* __restrict__ osc_a, const float* __restrict__ Bw,
    const float* __restrict__ Bb, const float* __restrict__ fw,
    const int* __restrict__ ptr, const int* __restrict__ csr,
    float* __restrict__ out, int n, int R, int nout, size_t nd)
{
    const int lane = threadIdx.x;
    const int r = blockIdx.x;
    if (r >= R) return;
    const int v = __builtin_amdgcn_readfirstlane(roots[r]);

    const float* P7 = Xall + 7 * nd;
    const float* P6 = Xall + 6 * nd;
    const unsigned base = ((unsigned)v << 6) + lane;
    int b = __builtin_amdgcn_readfirstlane(ptr[v]);
    int e = __builtin_amdgcn_readfirstlane(ptr[v + 1]);
    float x8 = wave_update(P7, P7[base], P6[base], lane, b, e, csr);

    float hin[9], hout[9];

    {   // pass 0: layer 0, zprev = X^s (same step)
        float4v wreg[16];
        const float* wp = Bw + (size_t)lane * 64;
#pragma unroll
        for (int q = 0; q < 16; ++q) wreg[q] = *(const float4v*)(wp + 4 * q);
        const float aj = osc_a[lane];
        const float bj = Bb[lane];
        float z = 0.f, u = 0.f;
#pragma unroll
        for (int s = 1; s <= 8; ++s) {
            float zp = (s < 8) ? Xall[(size_t)s * nd + base] : x8;
            float acc = fmaf(aj, z, bj);
#pragma unroll
            for (int q = 0; q < 16; ++q)
#pragma unroll
                for (int j = 0; j < 4; ++j)
                    acc = fmaf(bcast_lane(zp, 4 * q + j), wreg[q][j], acc);
            float t = acc > 0.f ? acc : 0.f;
            u += H * t;
            z += H * u;
            hout[s] = z;
        }
    }

    auto pass = [&](int j, int prev_step) {
        float4v wreg[16];
        const float* wp = Bw + (size_t)j * 4096 + (size_t)lane * 64;
#pragma unroll
        for (int q = 0; q < 16; ++q) wreg[q] = *(const float4v*)(wp + 4 * q);
        const float aj = osc_a[j * 64 + lane];
        const float bj = Bb[j * 64 + lane];
        float z = 0.f, u = 0.f;
#pragma unroll
        for (int s = 1; s <= 8; ++s) {
            float zp = prev_step ? hin[s - 1] : hin[s];
            float acc = fmaf(aj, z, bj);
#pragma unroll
            for (int q = 0; q < 16; ++q)
#pragma unroll
                for (int jj = 0; jj < 4; ++jj)
                    acc = fmaf(bcast_lane(zp, 4 * q + jj), wreg[q][jj], acc);
            float t = acc > 0.f ? acc : 0.f;
            u += H * t;
            z += H * u;
            hout[s] = z;
        }
    };

    hin[0] = 0.f;
#pragma unroll
    for (int i = 1; i <= 8; ++i) hin[i] = hout[i];
    pass(1, 0);                     // layer1: zprev = z0^s (same step)
    hin[0] = 0.f;
#pragma unroll
    for (int i = 1; i <= 8; ++i) hin[i] = hout[i];
    pass(2, 1);                     // layer2: zprev = z1^{s-1}
    hin[0] = 0.f;
#pragma unroll
    for (int i = 1; i <= 8; ++i) hin[i] = hout[i];
    pass(3, 1);                     // layer3: zprev = z2^{s-1}

    float z3 = hout[8];
    for (int o = 0; o < nout; ++o) {
        float p = z3 * fw[o * 64 + lane];
#pragma unroll
        for (int off = 32; off > 0; off >>= 1)
            p += __shfl_xor(p, off);
        if (lane == 0) out[r * nout + o] = p;
    }
}

extern "C" void kernel_launch(void* const* d_in, const int* in_sizes, int n_in,
                              void* d_out, int out_size, void* d_ws, size_t ws_size,
                              hipStream_t stream)
{
    const int*   xnode   = (const int*)d_in[0];
    const int*   edge    = (const int*)d_in[1];
    const int*   roots   = (const int*)d_in[2];
    const float* key_emb = (const float*)d_in[3];
    const float* val_emb = (const float*)d_in[4];
    const float* lw      = (const float*)d_in[5];
    const float* lb      = (const float*)d_in[6];
    const float* osc_a   = (const float*)d_in[7];
    const float* Bw      = (const float*)d_in[8];
    const float* Bb      = (const float*)d_in[9];
    const float* fw      = (const float*)d_in[10];

    const int n = in_sizes[0] / 2;
    const int E = in_sizes[1] / 2;
    const int R = in_sizes[2];
    const int K = in_sizes[3] / 64;
    const int nout = out_size / R;
    const int* erow = edge;           // sorted ascending (np.unique axis=1)
    const int* ecol = edge + E;       // adjacency array of the row-CSR, in place

    const size_t nd = (size_t)n * 64;
    float* Xall  = (float*)d_ws;                     // 8*nd (planes 0..7)
    float* Wk    = Xall + 8 * nd;                    // K*64
    float* Wv    = Wk + (size_t)K * 64;              // K*64
    int*   ptr   = (int*)(Wv + (size_t)K * 64);      // n+1
    int*   mask  = ptr + n + 1;                      // n
    int*   mask2 = mask + n;                         // n

    hipMemsetAsync(mask, 0, (size_t)(2 * n) * sizeof(int), stream);

    const int TBLK = (2 * K + 3) / 4;
    const int BBLK = (E + 255) / 256;
    const int RBLK = (R + 255) / 256;
    prep1_kernel<<<TBLK + BBLK + RBLK, 256, 0, stream>>>(
        key_emb, val_emb, lw, lb, Wk, Wv, K, erow, ptr, n, E,
        roots, mask, R, TBLK, BBLK);

    const int IBLK = (n * 64 + 255) / 256;
    const int MBLK = (E + 255) / 256;
    prep2_kernel<<<IBLK + MBLK, 256, 0, stream>>>(
        xnode, Wk, Wv, Xall, n, erow, ecol, mask, mask2, E, IBLK);

    const int nblocks = (n + 3) / 4;  // 4 waves (1 node each) per block
    for (int s = 1; s <= 6; ++s) {    // step s: reads planes s-1, s-2; writes s
        const float* xin = Xall + (size_t)(s - 1) * nd;
        const float* xm1 = (s == 1) ? xin : Xall + (size_t)(s - 2) * nd;
        wave_step<false><<<nblocks, 256, 0, stream>>>(
            xin, xm1, Xall + (size_t)s * nd, ptr, ecol, n, nullptr, nullptr);
    }
    // step 7: reads planes 6,5; writes plane 7; cone-restricted
    wave_step<true><<<nblocks, 256, 0, stream>>>(
        Xall + 6 * nd, Xall + 5 * nd, Xall + 7 * nd, ptr, ecol, n, mask, mask2);

    root_osc_final<<<R, 64, 0, stream>>>(
        Xall, roots, osc_a, Bw, Bb, fw, ptr, ecol,
        (float*)d_out, n, R, nout, nd);
}